// Round 9
// baseline (284.551 us; speedup 1.0000x reference)
//
#include <hip/hip_runtime.h>

// ---------------------------------------------------------------------------
// TransVLAD fused pipeline for MI355X (gfx950)
// Shapes: N=32, C=512, H=W=32 (P=1024), E=1024, G=8, D=128, K=64
// out: [N, K*D] fp32 (262144)
//
// R15: fuse K2 into K4. xe was only consumed by K4 (as the g-slice xg), and
// xg = W1g . xhat uses the SAME xhat tile the S-phase already stages. K4
// now stages a 3rd stream Ws = W1b[g*128..+128][64c] per round (W1b is 1MB,
// L2-resident) and accumulates acc_xg (per-wave 64d x 32p, +16 MFMA/round)
// next to acc_s in the SAME verified dbuf+counted-vmcnt skeleton (WAITV
// 3 -> 5). After ks loop: XG -> bf16 -> swizzled LDS (write d&7 == read
// l15&7 identity), agg phase unchanged. Removes: K2 kernel (~54us), 64MB
// xe writes + 64MB xe reads, one launch. K2's counted-vmcnt variant stays
// retired (implicated in R12/R13 container failures).
// k0/k1/k3n/k5 byte-identical to R14 (verified).
// ---------------------------------------------------------------------------

#define N_  32
#define C_  512
#define P_  1024
#define E_  1024
#define G_  8
#define D_  128
#define K_  64

typedef __attribute__((ext_vector_type(8))) short bf16x8;
typedef __attribute__((ext_vector_type(4))) float f32x4;

__device__ __forceinline__ unsigned short f2b(float f) {
    union { float f; unsigned u; } v; v.f = f;
    unsigned r = (v.u + 0x7FFFu + ((v.u >> 16) & 1u)) >> 16;
    return (unsigned short)r;
}
__device__ __forceinline__ float b2f(unsigned short h) {
    union { unsigned u; float f; } v; v.u = ((unsigned)h) << 16;
    return v.f;
}

// async global->LDS 16B copy: LDS dest must be wave-uniform base + lane*16
__device__ __forceinline__ void gl_lds16(const void* g, void* l) {
    __builtin_amdgcn_global_load_lds(
        (const __attribute__((address_space(1))) void*)g,
        (__attribute__((address_space(3))) void*)l, 16, 0, 0);
}

#define SB  __builtin_amdgcn_sched_barrier(0)
#define BAR __builtin_amdgcn_s_barrier()
#define WAITV(n_) asm volatile("s_waitcnt vmcnt(" #n_ ")" ::: "memory")

// ---------------------------------------------------------------------------
// K0: (bid<1024) W1 -> bf16 AND V[g][k][c] = sum_d Wc[k][d]*W1[g*128+d][c]
//     (bid in [1024,1152)) Wa[g][c] = sum_e W2[g][e]*W1[e][c], bf16.
__global__ __launch_bounds__(256) void k0_prep(const float* __restrict__ W1,
                                               const float* __restrict__ Wc,
                                               const float* __restrict__ W2,
                                               unsigned short* __restrict__ W1b,
                                               unsigned short* __restrict__ Vb,
                                               unsigned short* __restrict__ Wa) {
    int bid = blockIdx.x;
    int t = threadIdx.x;
    if (bid < 1024) {
        int i0 = bid * 512 + t;
        W1b[i0]       = f2b(W1[i0]);
        W1b[i0 + 256] = f2b(W1[i0 + 256]);
        int ch = bid & 1, k = (bid >> 1) & 63, g = bid >> 7;
        int c = ch * 256 + t;
        float acc = 0.f;
        #pragma unroll 8
        for (int d = 0; d < 128; ++d)
            acc += Wc[k * 128 + d] * W1[(g * 128 + d) * C_ + c];
        Vb[(g * 64 + k) * C_ + c] = f2b(acc);
    } else {
        __shared__ float red[256];
        int idx = bid - 1024;            // 0..127
        int g  = idx >> 4;               // 8 groups
        int c0 = (idx & 15) * 32;        // 16 col-chunks of 32
        int c  = c0 + (t & 31);
        int ec = t >> 5;                 // 8 e-chunks of 128
        float acc = 0.f;
        #pragma unroll 8
        for (int i = 0; i < 128; ++i) {
            int e = ec * 128 + i;
            acc += W2[g * E_ + e] * W1[e * C_ + c];
        }
        red[t] = acc;
        __syncthreads();
        if (t < 32) {
            float s = 0.f;
            #pragma unroll
            for (int j = 0; j < 8; ++j) s += red[j * 32 + t];
            Wa[g * C_ + c0 + t] = f2b(s);
        }
    }
}

// ---------------------------------------------------------------------------
// K1: per-pixel L2 norm over C, write x_hat transposed: xhat_t [N][P][C] bf16
__global__ __launch_bounds__(256) void k1_norm_transpose(const float* __restrict__ x,
                                                         unsigned short* __restrict__ xhat_t) {
    __shared__ short xc[128 * 256];   // [i][t]: c = (t>>6)*128+i, p = p0+(t&63)
    __shared__ float red[256];
    __shared__ float rn[64];
    int n = blockIdx.y;
    int p0 = blockIdx.x * 64;
    int t = threadIdx.x;
    int ps = t & 63, cs = t >> 6;

    float ss = 0.f;
    for (int i = 0; i < 128; ++i) {
        float v = x[((size_t)(n * C_ + cs * 128 + i)) * P_ + p0 + ps];
        ss += v * v;
        xc[i * 256 + t] = (short)f2b(v);     // lanes consecutive -> conflict-free
    }
    red[t] = ss;
    __syncthreads();
    if (t < 64) {
        float s = red[t] + red[64 + t] + red[128 + t] + red[192 + t];
        rn[t] = 1.0f / fmaxf(sqrtf(s), 1e-12f);
    }
    __syncthreads();

    float r = rn[ps];
    size_t base = ((size_t)(n * P_ + p0 + ps)) * C_ + cs * 128;
    #pragma unroll
    for (int jj = 0; jj < 16; ++jj) {
        bf16x8 o;
        #pragma unroll
        for (int j = 0; j < 8; ++j)
            o[j] = (short)f2b(b2f((unsigned short)xc[(jj * 8 + j) * 256 + t]) * r);
        *(bf16x8*)&xhat_t[base + jj * 8] = o;
    }
}

// ---------------------------------------------------------------------------
// K3n: att_s[n][g][p] = sigmoid( sum_c Wa[g][c] * xhat_t[n][p][c] )
// (R14-verified version)
__global__ __launch_bounds__(256) void k3n_att(const unsigned short* __restrict__ Wa,
                                               const unsigned short* __restrict__ xhat_t,
                                               float* __restrict__ att_s) {
    __shared__ __align__(16) short xh[64 * 512];   // 64 KB, swizzled
    __shared__ __align__(16) short wal[8 * 520];   // 8.3 KB, row stride 520 (debank)
    int n = blockIdx.y;
    int p0 = blockIdx.x * 64;
    int t = threadIdx.x;
    int w = t >> 6, l = t & 63, q = l >> 4, l15 = l & 15;

    #pragma unroll
    for (int i = 0; i < 16; ++i) {
        int ch = i * 256 + t;
        int row = ch >> 6, s = ch & 63;
        gl_lds16(&xhat_t[((size_t)(n * P_ + p0 + row)) * C_ + ((s ^ (row & 7)) * 8)],
                 &xh[ch * 8]);
    }
    #pragma unroll
    for (int i = 0; i < 2; ++i) {
        int ch = i * 256 + t;
        int row = ch >> 6, c8 = ch & 63;
        gl_lds16(&Wa[row * C_ + c8 * 8], &wal[row * 520 + c8 * 8]);
    }
    __syncthreads();

    f32x4 acc = (f32x4){0.f, 0.f, 0.f, 0.f};
    const bf16x8 zf = {};
    #pragma unroll
    for (int kstep = 0; kstep < 16; ++kstep) {
        bf16x8 av = *(const bf16x8*)&wal[(l15 & 7) * 520 + (kstep * 4 + q) * 8];
        bf16x8 af = (l15 < 8) ? av : zf;
        int row = w * 16 + l15;
        bf16x8 bf = *(const bf16x8*)&xh[row * 512 + (((kstep * 4 + q) ^ (row & 7)) * 8)];
        acc = __builtin_amdgcn_mfma_f32_16x16x32_bf16(af, bf, acc, 0, 0, 0);
    }

    if (q < 2) {
        int p = p0 + w * 16 + l15;
        #pragma unroll
        for (int r = 0; r < 4; ++r) {
            int g = q * 4 + r;
            att_s[((size_t)(n * G_ + g)) * P_ + p] = 1.0f / (1.0f + __expf(-acc[r]));
        }
    }
}

// ---------------------------------------------------------------------------
// K4f helpers (512-thread)
// One 40 KB S-tile (shorts): As [64][64] @ 0, Bs [128][64] @ 4096,
// Ws [128][64] @ 12288. All XOR-swizzled both sides.
__device__ __forceinline__ void stage_s3(short* sb,
                                         const unsigned short* __restrict__ Vb,
                                         const unsigned short* __restrict__ W1b,
                                         const unsigned short* __restrict__ xhat_t,
                                         int g, int n, int p0c, int k0, int t) {
    {
        int row = t >> 3, c8 = t & 7;
        gl_lds16(&Vb[(g * 64 + row) * C_ + k0 + ((c8 ^ (row & 7)) * 8)], &sb[t * 8]);
    }
    #pragma unroll
    for (int i = 0; i < 2; ++i) {
        int ch = i * 512 + t;
        int row = ch >> 3, c8 = ch & 7;
        gl_lds16(&xhat_t[((size_t)(n * P_ + p0c + row)) * C_ + k0 + ((c8 ^ (row & 7)) * 8)],
                 &sb[4096 + ch * 8]);
    }
    #pragma unroll
    for (int i = 0; i < 2; ++i) {
        int ch = i * 512 + t;
        int row = ch >> 3, c8 = ch & 7;
        gl_lds16(&W1b[(g * 128 + row) * C_ + k0 + ((c8 ^ (row & 7)) * 8)],
                 &sb[12288 + ch * 8]);
    }
}

// S-phase + XG-phase MFMA on one staged tile.
// acc_s: S = Vb (64k) x xhat (16p wave strip), acc_x: XG = W1g (64d) x xhat (32p)
__device__ __forceinline__ void mfma_sx(f32x4 accs[4], f32x4 accx[4][2], const short* sb,
                                        int w, int wd, int wp, int q, int l15) {
    #pragma unroll
    for (int kk = 0; kk < 2; ++kk) {
        int col = ((kk * 4 + q) ^ (l15 & 7)) * 8;
        bf16x8 af[4], bfr, axf[4], bxf[2];
        #pragma unroll
        for (int mi = 0; mi < 4; ++mi)
            af[mi] = *(const bf16x8*)&sb[(mi * 16 + l15) * 64 + col];
        bfr = *(const bf16x8*)&sb[4096 + (w * 16 + l15) * 64 + col];
        #pragma unroll
        for (int mi = 0; mi < 4; ++mi)
            axf[mi] = *(const bf16x8*)&sb[12288 + (wd * 64 + mi * 16 + l15) * 64 + col];
        #pragma unroll
        for (int ni = 0; ni < 2; ++ni)
            bxf[ni] = *(const bf16x8*)&sb[4096 + (wp * 32 + ni * 16 + l15) * 64 + col];
        #pragma unroll
        for (int mi = 0; mi < 4; ++mi)
            accs[mi] = __builtin_amdgcn_mfma_f32_16x16x32_bf16(af[mi], bfr, accs[mi], 0, 0, 0);
        #pragma unroll
        for (int mi = 0; mi < 4; ++mi)
            #pragma unroll
            for (int ni = 0; ni < 2; ++ni)
                accx[mi][ni] = __builtin_amdgcn_mfma_f32_16x16x32_bf16(axf[mi], bxf[ni], accx[mi][ni], 0, 0, 0);
    }
}

// ---------------------------------------------------------------------------
// K4f: fused linear1(group slice) -> assignment -> softmax -> gate -> agg
// grid (16, 32) x 512 threads. Double-buffered 40KB S-tiles, counted vmcnt(5).
__global__ __launch_bounds__(512, 4) void k4_fused(const unsigned short* __restrict__ Vb,
                                                   const unsigned short* __restrict__ W1b,
                                                   const unsigned short* __restrict__ xhat_t,
                                                   const float* __restrict__ att_s,
                                                   float* __restrict__ agg_part,
                                                   float* __restrict__ wsum_part) {
    __shared__ __align__(16) char smem[81920];
    short* S0   = (short*)smem;                 // 40 KB
    short* S1   = (short*)(smem + 40960);       // 40 KB
    short* wlds = (short*)smem;                 // [64][136] 17.4 KB alias over S0
    short* xgb  = (short*)(smem + 40960);       // [128][128] 32 KB alias over S1
    float* wred = (float*)smem;                 // [8][64] 2 KB epilogue alias

    // XCD-aware remap (bijective: 512 blocks, 512 % 8 == 0)
    int b = blockIdx.y * 16 + blockIdx.x;
    int work = (b & 7) * 64 + (b >> 3);
    int n = work >> 4, g = work & 7, ph = (work >> 3) & 1;

    int t = threadIdx.x;
    int w = t >> 6, l = t & 63, q = l >> 4, l15 = l & 15;
    int kh = w >> 2, dq = w & 3;     // agg-phase wave tile (32k x 32d)
    int wd = w >> 2, wp = w & 3;     // xg-phase wave tile (64d x 32p)

    f32x4 acc_a[2][2];
    #pragma unroll
    for (int mi = 0; mi < 2; ++mi)
        #pragma unroll
        for (int ni = 0; ni < 2; ++ni)
            acc_a[mi][ni] = (f32x4){0.f, 0.f, 0.f, 0.f};
    float wsp[16];
    #pragma unroll
    for (int j = 0; j < 16; ++j) wsp[j] = 0.f;

#define RND(CUR, NXT, KN) \
    stage_s3(NXT, Vb, W1b, xhat_t, g, n, p0c, (KN) * 64, t); \
    WAITV(5); BAR; SB; \
    mfma_sx(acc_s, acc_x, CUR, w, wd, wp, q, l15); \
    BAR; SB;

    #pragma unroll 1
    for (int cc = 0; cc < 4; ++cc) {
        int p0c = ph * 512 + cc * 128;

        // att gate (oldest VMEM op; drained by round-0's vmcnt(5))
        float av = att_s[(((size_t)(n * G_ + g)) * P_) + p0c + w * 16 + l15];

        f32x4 acc_s[4];
        f32x4 acc_x[4][2];
        #pragma unroll
        for (int mi = 0; mi < 4; ++mi) {
            acc_s[mi] = (f32x4){0.f, 0.f, 0.f, 0.f};
            #pragma unroll
            for (int ni = 0; ni < 2; ++ni)
                acc_x[mi][ni] = (f32x4){0.f, 0.f, 0.f, 0.f};
        }

        // ---- fused S (Vb.xhat) + XG (W1g.xhat) over BK=64, dbuf ----
        stage_s3(S0, Vb, W1b, xhat_t, g, n, p0c, 0, t);   // prologue ks=0
        RND(S0, S1, 1)
        RND(S1, S0, 2)
        RND(S0, S1, 3)
        RND(S1, S0, 4)
        RND(S0, S1, 5)
        RND(S1, S0, 6)
        RND(S0, S1, 7)
        WAITV(0); BAR; SB;
        mfma_sx(acc_s, acc_x, S1, w, wd, wp, q, l15);     // ks=7
        BAR; SB;

        // ---- softmax over k + gate (wave strip = 16 pixels) -> wlds ----
        {
            float m = -1e30f;
            #pragma unroll
            for (int mi = 0; mi < 4; ++mi)
                #pragma unroll
                for (int r = 0; r < 4; ++r)
                    m = fmaxf(m, acc_s[mi][r]);
            m = fmaxf(m, __shfl_xor(m, 16));
            m = fmaxf(m, __shfl_xor(m, 32));
            float s = 0.f;
            #pragma unroll
            for (int mi = 0; mi < 4; ++mi)
                #pragma unroll
                for (int r = 0; r < 4; ++r) {
                    float e = __expf(acc_s[mi][r] - m);
                    acc_s[mi][r] = e;
                    s += e;
                }
            s += __shfl_xor(s, 16);
            s += __shfl_xor(s, 32);

            float scale = av / s;   // av pre-sigmoided

            #pragma unroll
            for (int mi = 0; mi < 4; ++mi)
                #pragma unroll
                for (int r = 0; r < 4; ++r) {
                    float wv = acc_s[mi][r] * scale;
                    wsp[mi * 4 + r] += wv;
                    wlds[(mi * 16 + q * 4 + r) * 136 + (w * 16 + l15)] = (short)f2b(wv);
                }
        }

        // ---- XG -> bf16 -> xgb LDS (both-sides XOR swizzle, d&7 keyed) ----
        #pragma unroll
        for (int mi = 0; mi < 4; ++mi)
            #pragma unroll
            for (int ni = 0; ni < 2; ++ni)
                #pragma unroll
                for (int r = 0; r < 4; ++r) {
                    int d = wd * 64 + mi * 16 + q * 4 + r;
                    int p = wp * 32 + ni * 16 + l15;
                    xgb[d * 128 + (((p >> 3) ^ (d & 7)) * 8) + (p & 7)] = (short)f2b(acc_x[mi][ni][r]);
                }
        __syncthreads();   // wlds + xgb visible

        // ---- agg MFMA: A = w [64k x 128p], B = xg [128d x 128p] (NT) ----
        #pragma unroll
        for (int pk = 0; pk < 4; ++pk) {
            bf16x8 a2[2], b2[2];
            #pragma unroll
            for (int mi = 0; mi < 2; ++mi)
                a2[mi] = *(const bf16x8*)&wlds[(kh * 32 + mi * 16 + l15) * 136 + pk * 32 + q * 8];
            #pragma unroll
            for (int ni = 0; ni < 2; ++ni)
                b2[ni] = *(const bf16x8*)&xgb[(dq * 32 + ni * 16 + l15) * 128
                                              + (((pk * 4 + q) ^ (l15 & 7)) * 8)];
            #pragma unroll
            for (int mi = 0; mi < 2; ++mi)
                #pragma unroll
                for (int ni = 0; ni < 2; ++ni)
                    acc_a[mi][ni] = __builtin_amdgcn_mfma_f32_16x16x32_bf16(a2[mi], b2[ni], acc_a[mi][ni], 0, 0, 0);
        }
        __syncthreads();   // reads done before next cc re-stages
    }

    // ---- epilogue: disjoint partials, no atomics ----
    size_t base = (((size_t)(n * G_ + g)) * 2 + ph) * 64;
    #pragma unroll
    for (int mi = 0; mi < 2; ++mi)
        #pragma unroll
        for (int ni = 0; ni < 2; ++ni)
            #pragma unroll
            for (int r = 0; r < 4; ++r) {
                int k = kh * 32 + mi * 16 + q * 4 + r;
                int d = dq * 32 + ni * 16 + l15;
                agg_part[(base + k) * 128 + d] = acc_a[mi][ni][r];
            }

    // wsum: per-wave k-sums -> LDS -> one [64] vector per block
    #pragma unroll
    for (int j = 0; j < 16; ++j) {
        float v = wsp[j];
        v += __shfl_xor(v, 1);
        v += __shfl_xor(v, 2);
        v += __shfl_xor(v, 4);
        v += __shfl_xor(v, 8);
        if (l15 == 0) {
            int k = (j >> 2) * 16 + q * 4 + (j & 3);
            wred[w * 64 + k] = v;
        }
    }
    __syncthreads();
    if (t < 64) {
        float s = 0.f;
        #pragma unroll
        for (int wv = 0; wv < 8; ++wv)
            s += wred[wv * 64 + t];
        wsum_part[(((size_t)(n * G_ + g)) * 2 + ph) * 64 + t] = s;
    }
}

// ---------------------------------------------------------------------------
// K5: vlad[n][k][d] = sum_{g,ph} agg_part - (sum) * centroids
__global__ __launch_bounds__(256) void k5_final(const float* __restrict__ agg_part,
                                                const float* __restrict__ wsum_part,
                                                const float* __restrict__ centroids,
                                                float* __restrict__ out) {
    int idx = blockIdx.x * 256 + threadIdx.x;
    int d = idx & 127;
    int k = (idx >> 7) & 63;
    int n = idx >> 13;
    float ws = 0.f;
    #pragma unroll
    for (int g = 0; g < 8; ++g)
        #pragma unroll
        for (int ph = 0; ph < 2; ++ph)
            ws += wsum_part[(((size_t)(n * G_ + g)) * 2 + ph) * 64 + k];
    float agg = 0.f;
    #pragma unroll
    for (int g = 0; g < 8; ++g)
        #pragma unroll
        for (int ph = 0; ph < 2; ++ph)
            agg += agg_part[(((((size_t)(n * G_ + g)) * 2 + ph) * 64) + k) * 128 + d];
    out[idx] = agg - ws * centroids[k * 128 + d];
}

// ---------------------------------------------------------------------------
extern "C" void kernel_launch(void* const* d_in, const int* in_sizes, int n_in,
                              void* d_out, int out_size, void* d_ws, size_t ws_size,
                              hipStream_t stream) {
    const float* x         = (const float*)d_in[0];
    const float* W1        = (const float*)d_in[1];
    const float* W2        = (const float*)d_in[2];
    const float* Wc        = (const float*)d_in[3];
    const float* centroids = (const float*)d_in[4];
    float* out = (float*)d_out;

    // Workspace layout (xe region now unused; offsets unchanged):
    //   W1b      [E*C]        bf16   1,048,576 B @ 0
    //   Vb       [G*K*C]      bf16     524,288 B @ 1,048,576
    //   xhat_t   [N*P*C]      bf16  33,554,432 B @ 1,572,864
    //   (xe dead)                                @ 35,127,296
    //   att_s    [N*G*P]      f32    1,048,576 B @ 102,236,160
    //   agg_part [N*G*2*K*D]  f32   16,777,216 B @ 103,284,736
    //   wsum_part[N*G*2*K]    f32      131,072 B @ 120,061,952
    //   Wa       [G*C]        bf16       8,192 B @ 120,193,024
    char* ws = (char*)d_ws;
    unsigned short* W1b      = (unsigned short*)(ws + 0);
    unsigned short* Vb       = (unsigned short*)(ws + 1048576);
    unsigned short* xhat_t   = (unsigned short*)(ws + 1572864);
    float*          att_s    = (float*)(ws + 102236160);
    float*          agg_part = (float*)(ws + 103284736);
    float*          wsum_part= (float*)(ws + 120061952);
    unsigned short* Wa       = (unsigned short*)(ws + 120193024);

    hipLaunchKernelGGL(k0_prep,        dim3(1152), dim3(256), 0, stream, W1, Wc, W2, W1b, Vb, Wa);
    hipLaunchKernelGGL(k1_norm_transpose, dim3(16, 32), dim3(256), 0, stream, x, xhat_t);
    hipLaunchKernelGGL(k3n_att,        dim3(16, 32), dim3(256), 0, stream, Wa, xhat_t, att_s);
    hipLaunchKernelGGL(k4_fused,       dim3(16, 32), dim3(512), 0, stream, Vb, W1b, xhat_t,
                       att_s, agg_part, wsum_part);
    hipLaunchKernelGGL(k5_final,       dim3(1024), dim3(256), 0, stream,
                       agg_part, wsum_part, centroids, out);
}

// Round 10
// 212.260 us; speedup vs baseline: 1.3406x; 1.3406x over previous
//
#include <hip/hip_runtime.h>

// ---------------------------------------------------------------------------
// TransVLAD fused pipeline for MI355X (gfx950)
// Shapes: N=32, C=512, H=W=32 (P=1024), E=1024, G=8, D=128, K=64
// out: [N, K*D] fp32 (262144)
//
// R16: revert R15's K2->K4 fusion (FETCH 255MB: the Ws stream pushed the
// per-XCD working set past 4MB L2 -> xhat reuse collapsed -> HBM-bound
// 152us). Base = R14 (214.5us verified). New: fold att into K1 (delete
// k3n): K1's block already holds the exact xhat tile k3n re-read (32MB);
// att = sigmoid(sum_c Wa[g][c]*xhat[p][c]) accumulated in-register during
// the existing jj loop (Wa in 8KB LDS, wave-uniform broadcast reads),
// 2-stage LDS reduce over the 4 c-waves. LDS 78.8KB -> still 2 blocks/CU.
// k0/k2/k4/k5 byte-identical to R14. K2-dbuf stays retired.
// ---------------------------------------------------------------------------

#define N_  32
#define C_  512
#define P_  1024
#define E_  1024
#define G_  8
#define D_  128
#define K_  64

typedef __attribute__((ext_vector_type(8))) short bf16x8;
typedef __attribute__((ext_vector_type(4))) float f32x4;

__device__ __forceinline__ unsigned short f2b(float f) {
    union { float f; unsigned u; } v; v.f = f;
    unsigned r = (v.u + 0x7FFFu + ((v.u >> 16) & 1u)) >> 16;
    return (unsigned short)r;
}
__device__ __forceinline__ float b2f(unsigned short h) {
    union { unsigned u; float f; } v; v.u = ((unsigned)h) << 16;
    return v.f;
}

// async global->LDS 16B copy: LDS dest must be wave-uniform base + lane*16
__device__ __forceinline__ void gl_lds16(const void* g, void* l) {
    __builtin_amdgcn_global_load_lds(
        (const __attribute__((address_space(1))) void*)g,
        (__attribute__((address_space(3))) void*)l, 16, 0, 0);
}

#define SB  __builtin_amdgcn_sched_barrier(0)
#define BAR __builtin_amdgcn_s_barrier()
#define WAITV(n_) asm volatile("s_waitcnt vmcnt(" #n_ ")" ::: "memory")

// ---------------------------------------------------------------------------
// K0: (bid<1024) W1 -> bf16 AND V[g][k][c] = sum_d Wc[k][d]*W1[g*128+d][c]
//     (bid in [1024,1152)) Wa[g][c] = sum_e W2[g][e]*W1[e][c], bf16.
__global__ __launch_bounds__(256) void k0_prep(const float* __restrict__ W1,
                                               const float* __restrict__ Wc,
                                               const float* __restrict__ W2,
                                               unsigned short* __restrict__ W1b,
                                               unsigned short* __restrict__ Vb,
                                               unsigned short* __restrict__ Wa) {
    int bid = blockIdx.x;
    int t = threadIdx.x;
    if (bid < 1024) {
        int i0 = bid * 512 + t;
        W1b[i0]       = f2b(W1[i0]);
        W1b[i0 + 256] = f2b(W1[i0 + 256]);
        int ch = bid & 1, k = (bid >> 1) & 63, g = bid >> 7;
        int c = ch * 256 + t;
        float acc = 0.f;
        #pragma unroll 8
        for (int d = 0; d < 128; ++d)
            acc += Wc[k * 128 + d] * W1[(g * 128 + d) * C_ + c];
        Vb[(g * 64 + k) * C_ + c] = f2b(acc);
    } else {
        __shared__ float red[256];
        int idx = bid - 1024;            // 0..127
        int g  = idx >> 4;               // 8 groups
        int c0 = (idx & 15) * 32;        // 16 col-chunks of 32
        int c  = c0 + (t & 31);
        int ec = t >> 5;                 // 8 e-chunks of 128
        float acc = 0.f;
        #pragma unroll 8
        for (int i = 0; i < 128; ++i) {
            int e = ec * 128 + i;
            acc += W2[g * E_ + e] * W1[e * C_ + c];
        }
        red[t] = acc;
        __syncthreads();
        if (t < 32) {
            float s = 0.f;
            #pragma unroll
            for (int j = 0; j < 8; ++j) s += red[j * 32 + t];
            Wa[g * C_ + c0 + t] = f2b(s);
        }
    }
}

// ---------------------------------------------------------------------------
// K1: per-pixel L2 norm + transpose + FUSED att gate.
// xhat_t [N][P][C] bf16; att_s[n][g][p] = sigmoid(sum_c Wa[g][c]*xhat[p][c]).
// LDS: xc 64K + waL 8K + attP 4K + red 1K = 78.8 KB (2 blocks/CU).
__global__ __launch_bounds__(256) void k1_norm_att(const float* __restrict__ x,
                                                   const unsigned short* __restrict__ Wa,
                                                   unsigned short* __restrict__ xhat_t,
                                                   float* __restrict__ att_s) {
    __shared__ short xc[128 * 256];   // [i][t]: c = (t>>6)*128+i, p = p0+(t&63)
    __shared__ short waL[8 * 512];    // Wa bf16
    __shared__ float attP[2 * 64 * 8];
    __shared__ float red[256];
    int n = blockIdx.y;
    int p0 = blockIdx.x * 64;
    int t = threadIdx.x;
    int ps = t & 63, cs = t >> 6;     // cs is wave-uniform

    // stage Wa (coalesced 16B copies; k0 ordered before k1 on the stream)
    #pragma unroll
    for (int i = 0; i < 2; ++i) {
        int ch = i * 256 + t;
        *(bf16x8*)&waL[ch * 8] = *(const bf16x8*)&Wa[ch * 8];
    }

    float ss = 0.f;
    for (int i = 0; i < 128; ++i) {
        float v = x[((size_t)(n * C_ + cs * 128 + i)) * P_ + p0 + ps];
        ss += v * v;
        xc[i * 256 + t] = (short)f2b(v);     // lanes consecutive -> conflict-free
    }
    red[t] = ss;
    __syncthreads();
    if (t < 64) {
        float s = red[t] + red[64 + t] + red[128 + t] + red[192 + t];
        red[t] = 1.0f / fmaxf(sqrtf(s), 1e-12f);   // reuse red for rn
    }
    __syncthreads();

    float r = red[ps];
    float accA[8];
    #pragma unroll
    for (int g = 0; g < 8; ++g) accA[g] = 0.f;

    size_t base = ((size_t)(n * P_ + p0 + ps)) * C_ + cs * 128;
    #pragma unroll
    for (int jj = 0; jj < 16; ++jj) {
        bf16x8 o;
        float xv[8];
        #pragma unroll
        for (int j = 0; j < 8; ++j) {
            xv[j] = b2f((unsigned short)xc[(jj * 8 + j) * 256 + t]) * r;
            o[j] = (short)f2b(xv[j]);
        }
        *(bf16x8*)&xhat_t[base + jj * 8] = o;
        // att partial: this thread owns c-range [cs*128+jj*8, +8) of pixel ps
        #pragma unroll
        for (int g = 0; g < 8; ++g) {
            bf16x8 wa = *(const bf16x8*)&waL[g * 512 + cs * 128 + jj * 8];  // broadcast
            #pragma unroll
            for (int j = 0; j < 8; ++j)
                accA[g] += b2f((unsigned short)wa[j]) * xv[j];
        }
    }

    // reduce over the 4 c-waves: stage 1 (cs odd writes), stage 2 (cs even adds)
    if (cs & 1) {
        #pragma unroll
        for (int g = 0; g < 8; ++g)
            attP[((cs >> 1) * 64 + ps) * 8 + g] = accA[g];
    }
    __syncthreads();
    if (!(cs & 1)) {
        #pragma unroll
        for (int g = 0; g < 8; ++g)
            attP[((cs >> 1) * 64 + ps) * 8 + g] += accA[g];
    }
    __syncthreads();
    if (cs == 0) {
        #pragma unroll
        for (int g = 0; g < 8; ++g) {
            float s = attP[(0 * 64 + ps) * 8 + g] + attP[(1 * 64 + ps) * 8 + g];
            att_s[((size_t)(n * G_ + g)) * P_ + p0 + ps] = 1.0f / (1.0f + __expf(-s));
        }
    }
}

// ---------------------------------------------------------------------------
// K2: xe[n][e][p] = sum_c W1b[e][c] * xhat_t[n][p][c]   (bf16 MFMA GEMM, NT)
// grid (64, 32). BK=64, XOR-swizzled LDS columns (chunk ^= row&7).
// (R14-verified version)
__global__ __launch_bounds__(256) void k2_gemm_xe(const unsigned short* __restrict__ W1b,
                                                  const unsigned short* __restrict__ xhat_t,
                                                  unsigned short* __restrict__ xe) {
    __shared__ __align__(16) short As[128 * 64];
    __shared__ __align__(16) short Bs[128 * 64];
    int n = blockIdx.y;
    int e0 = (blockIdx.x >> 3) * 128;
    int p0 = (blockIdx.x & 7) * 128;
    int t = threadIdx.x;
    int w = t >> 6, l = t & 63, q = l >> 4, l15 = l & 15;
    int wr = w >> 1, wc = w & 1;

    f32x4 acc[4][4];
    #pragma unroll
    for (int mi = 0; mi < 4; ++mi)
        #pragma unroll
        for (int ni = 0; ni < 4; ++ni)
            acc[mi][ni] = (f32x4){0.f, 0.f, 0.f, 0.f};

    for (int ks = 0; ks < 8; ++ks) {
        int k0 = ks * 64;
        #pragma unroll
        for (int i = 0; i < 4; ++i) {
            int ch = i * 256 + t;
            int row = ch >> 3, c8 = ch & 7;
            gl_lds16(&W1b[(e0 + row) * C_ + k0 + ((c8 ^ (row & 7)) * 8)], &As[ch * 8]);
        }
        #pragma unroll
        for (int i = 0; i < 4; ++i) {
            int ch = i * 256 + t;
            int row = ch >> 3, c8 = ch & 7;
            gl_lds16(&xhat_t[((size_t)(n * P_ + p0 + row)) * C_ + k0 + ((c8 ^ (row & 7)) * 8)], &Bs[ch * 8]);
        }
        __syncthreads();

        #pragma unroll
        for (int kk = 0; kk < 2; ++kk) {
            bf16x8 af[4], bf[4];
            #pragma unroll
            for (int mi = 0; mi < 4; ++mi)
                af[mi] = *(const bf16x8*)&As[(wr * 64 + mi * 16 + l15) * 64 + (((kk * 4 + q) ^ (l15 & 7)) * 8)];
            #pragma unroll
            for (int ni = 0; ni < 4; ++ni)
                bf[ni] = *(const bf16x8*)&Bs[(wc * 64 + ni * 16 + l15) * 64 + (((kk * 4 + q) ^ (l15 & 7)) * 8)];
            #pragma unroll
            for (int mi = 0; mi < 4; ++mi)
                #pragma unroll
                for (int ni = 0; ni < 4; ++ni)
                    acc[mi][ni] = __builtin_amdgcn_mfma_f32_16x16x32_bf16(af[mi], bf[ni], acc[mi][ni], 0, 0, 0);
        }
        __syncthreads();
    }

    #pragma unroll
    for (int mi = 0; mi < 4; ++mi) {
        #pragma unroll
        for (int ni = 0; ni < 4; ++ni) {
            #pragma unroll
            for (int r = 0; r < 4; ++r) {
                int e = e0 + wr * 64 + mi * 16 + q * 4 + r;
                int p = p0 + wc * 64 + ni * 16 + l15;
                xe[((size_t)(n * E_ + e)) * P_ + p] = f2b(acc[mi][ni][r]);
            }
        }
    }
}

// ---------------------------------------------------------------------------
// K4 helpers (512-thread variants)
// stage one 24 KB S-tile: As [64][64] @ sb, Bs [128][64] @ sb+4096 (shorts)
__device__ __forceinline__ void stage_s(short* sb, const unsigned short* __restrict__ Vb,
                                        const unsigned short* __restrict__ xhat_t,
                                        int g, int n, int p0c, int k0, int t) {
    {
        int row = t >> 3, c8 = t & 7;
        gl_lds16(&Vb[(g * 64 + row) * C_ + k0 + ((c8 ^ (row & 7)) * 8)], &sb[t * 8]);
    }
    #pragma unroll
    for (int i = 0; i < 2; ++i) {
        int ch = i * 512 + t;
        int row = ch >> 3, c8 = ch & 7;
        gl_lds16(&xhat_t[((size_t)(n * P_ + p0c + row)) * C_ + k0 + ((c8 ^ (row & 7)) * 8)],
                 &sb[4096 + ch * 8]);
    }
}

__device__ __forceinline__ void stage_xg(short* xglds, const unsigned short* __restrict__ xe,
                                         int n, int g, int p0c, int t) {
    #pragma unroll
    for (int i = 0; i < 4; ++i) {
        int ch = i * 512 + t;
        int row = ch >> 4, c16 = ch & 15;
        gl_lds16(&xe[((size_t)(n * E_ + g * 128 + row)) * P_ + p0c + ((c16 ^ (row & 7)) * 8)],
                 &xglds[ch * 8]);
    }
}

__device__ __forceinline__ void mfma_s(f32x4 acc[4], const short* sb, int w, int q, int l15) {
    #pragma unroll
    for (int kk = 0; kk < 2; ++kk) {
        bf16x8 af[4], bfr;
        #pragma unroll
        for (int mi = 0; mi < 4; ++mi)
            af[mi] = *(const bf16x8*)&sb[(mi * 16 + l15) * 64 + (((kk * 4 + q) ^ (l15 & 7)) * 8)];
        bfr = *(const bf16x8*)&sb[4096 + (w * 16 + l15) * 64 + (((kk * 4 + q) ^ (l15 & 7)) * 8)];
        #pragma unroll
        for (int mi = 0; mi < 4; ++mi)
            acc[mi] = __builtin_amdgcn_mfma_f32_16x16x32_bf16(af[mi], bfr, acc[mi], 0, 0, 0);
    }
}

// ---------------------------------------------------------------------------
// K4: fused assignment -> softmax -> gate -> aggregation per (n, g, ph)
// grid (16, 32) x 512 threads. Double-buffered S-tile, counted-vmcnt rounds.
// (R14-verified version)
__global__ __launch_bounds__(512, 4) void k4_assign_agg(const unsigned short* __restrict__ Vb,
                                                        const unsigned short* __restrict__ xhat_t,
                                                        const unsigned short* __restrict__ xe,
                                                        const float* __restrict__ att_s,
                                                        float* __restrict__ agg_part,
                                                        float* __restrict__ wsum_part) {
    __shared__ __align__(16) char smem[81920];
    short* S0    = (short*)smem;                 // 24 KB: As 8K + Bs 16K
    short* S1    = (short*)(smem + 24576);       // 24 KB
    short* xglds = (short*)(smem + 49152);       // [128][128] 32 KB (swizzled)
    short* wlds  = (short*)smem;                 // [64][136] 17.4 KB alias over S0
    float* wred  = (float*)smem;                 // [8][64] 2 KB epilogue alias

    // XCD-aware remap (bijective: 512 blocks, 512 % 8 == 0)
    int b = blockIdx.y * 16 + blockIdx.x;
    int work = (b & 7) * 64 + (b >> 3);
    int n = work >> 4, g = work & 7, ph = (work >> 3) & 1;

    int t = threadIdx.x;
    int w = t >> 6, l = t & 63, q = l >> 4, l15 = l & 15;
    int kh = w >> 2, dq = w & 3;

    f32x4 acc_a[2][2];
    #pragma unroll
    for (int mi = 0; mi < 2; ++mi)
        #pragma unroll
        for (int ni = 0; ni < 2; ++ni)
            acc_a[mi][ni] = (f32x4){0.f, 0.f, 0.f, 0.f};
    float wsp[16];
    #pragma unroll
    for (int j = 0; j < 16; ++j) wsp[j] = 0.f;

#define RND(CUR, NXT, KN) \
    stage_s(NXT, Vb, xhat_t, g, n, p0c, (KN) * 64, t); \
    WAITV(3); BAR; SB; \
    mfma_s(acc_s, CUR, w, q, l15); \
    BAR; SB;

    #pragma unroll 1
    for (int cc = 0; cc < 4; ++cc) {
        int p0c = ph * 512 + cc * 128;

        // att gate value for this wave's 16-pixel strip (oldest VMEM op;
        // drained by round-0's vmcnt(3), consumed in softmax)
        float av = att_s[(((size_t)(n * G_ + g)) * P_) + p0c + w * 16 + l15];

        f32x4 acc_s[4];
        #pragma unroll
        for (int mi = 0; mi < 4; ++mi)
            acc_s[mi] = (f32x4){0.f, 0.f, 0.f, 0.f};

        // ---- Phase S: S = Vb[g] (64xC) * xhat^T (Cx128), BK=64, dbuf ----
        stage_s(S0, Vb, xhat_t, g, n, p0c, 0, t);       // prologue: ks=0
        RND(S0, S1, 1)                                  // reads ks0, stages ks1
        RND(S1, S0, 2)
        RND(S0, S1, 3)
        RND(S1, S0, 4)
        RND(S0, S1, 5)
        RND(S1, S0, 6)
        // round reading ks=6: stage ks=7 AND xg (HBM) -> both stay in flight
        stage_s(S1, Vb, xhat_t, g, n, p0c, 448, t);
        stage_xg(xglds, xe, n, g, p0c, t);
        WAITV(7); BAR; SB;
        mfma_s(acc_s, S0, w, q, l15);
        BAR; SB;
        // round reading ks=7: xg (4 ops) still outstanding
        WAITV(4); BAR; SB;
        mfma_s(acc_s, S1, w, q, l15);
        BAR; SB;

        // ---- softmax over k + gate (wave strip = 16 pixels) ----
        {
            float m = -1e30f;
            #pragma unroll
            for (int mi = 0; mi < 4; ++mi)
                #pragma unroll
                for (int r = 0; r < 4; ++r)
                    m = fmaxf(m, acc_s[mi][r]);
            m = fmaxf(m, __shfl_xor(m, 16));
            m = fmaxf(m, __shfl_xor(m, 32));
            float s = 0.f;
            #pragma unroll
            for (int mi = 0; mi < 4; ++mi)
                #pragma unroll
                for (int r = 0; r < 4; ++r) {
                    float e = __expf(acc_s[mi][r] - m);
                    acc_s[mi][r] = e;
                    s += e;
                }
            s += __shfl_xor(s, 16);
            s += __shfl_xor(s, 32);

            float scale = av / s;   // av pre-sigmoided

            #pragma unroll
            for (int mi = 0; mi < 4; ++mi)
                #pragma unroll
                for (int r = 0; r < 4; ++r) {
                    float wv = acc_s[mi][r] * scale;
                    wsp[mi * 4 + r] += wv;
                    wlds[(mi * 16 + q * 4 + r) * 136 + (w * 16 + l15)] = (short)f2b(wv);
                }
        }
        __syncthreads();   // drains xg DMA (vmcnt) + wlds writes (lgkmcnt)

        // ---- agg MFMA: A = w [64k x 128p], B = xg [128d x 128p] (NT) ----
        // wave (kh,dq): 32 k-rows x 32 d-cols, full 128-p reduction
        #pragma unroll
        for (int pk = 0; pk < 4; ++pk) {
            bf16x8 a2[2], b2[2];
            #pragma unroll
            for (int mi = 0; mi < 2; ++mi)
                a2[mi] = *(const bf16x8*)&wlds[(kh * 32 + mi * 16 + l15) * 136 + pk * 32 + q * 8];
            #pragma unroll
            for (int ni = 0; ni < 2; ++ni)
                b2[ni] = *(const bf16x8*)&xglds[(dq * 32 + ni * 16 + l15) * 128
                                                + (((pk * 4 + q) ^ (l15 & 7)) * 8)];
            #pragma unroll
            for (int mi = 0; mi < 2; ++mi)
                #pragma unroll
                for (int ni = 0; ni < 2; ++ni)
                    acc_a[mi][ni] = __builtin_amdgcn_mfma_f32_16x16x32_bf16(a2[mi], b2[ni], acc_a[mi][ni], 0, 0, 0);
        }
        __syncthreads();   // xglds/wlds reads done before next cc re-stages
    }

    // ---- epilogue: disjoint partials, no atomics ----
    size_t base = (((size_t)(n * G_ + g)) * 2 + ph) * 64;
    #pragma unroll
    for (int mi = 0; mi < 2; ++mi)
        #pragma unroll
        for (int ni = 0; ni < 2; ++ni)
            #pragma unroll
            for (int r = 0; r < 4; ++r) {
                int k = kh * 32 + mi * 16 + q * 4 + r;
                int d = dq * 32 + ni * 16 + l15;
                agg_part[(base + k) * 128 + d] = acc_a[mi][ni][r];
            }

    // wsum: per-wave k-sums -> LDS -> one [64] vector per block
    #pragma unroll
    for (int j = 0; j < 16; ++j) {
        float v = wsp[j];
        v += __shfl_xor(v, 1);
        v += __shfl_xor(v, 2);
        v += __shfl_xor(v, 4);
        v += __shfl_xor(v, 8);
        if (l15 == 0) {
            int k = (j >> 2) * 16 + q * 4 + (j & 3);
            wred[w * 64 + k] = v;
        }
    }
    __syncthreads();
    if (t < 64) {
        float s = 0.f;
        #pragma unroll
        for (int wv = 0; wv < 8; ++wv)
            s += wred[wv * 64 + t];
        wsum_part[(((size_t)(n * G_ + g)) * 2 + ph) * 64 + t] = s;
    }
}

// ---------------------------------------------------------------------------
// K5: vlad[n][k][d] = sum_{g,ph} agg_part - (sum) * centroids
__global__ __launch_bounds__(256) void k5_final(const float* __restrict__ agg_part,
                                                const float* __restrict__ wsum_part,
                                                const float* __restrict__ centroids,
                                                float* __restrict__ out) {
    int idx = blockIdx.x * 256 + threadIdx.x;
    int d = idx & 127;
    int k = (idx >> 7) & 63;
    int n = idx >> 13;
    float ws = 0.f;
    #pragma unroll
    for (int g = 0; g < 8; ++g)
        #pragma unroll
        for (int ph = 0; ph < 2; ++ph)
            ws += wsum_part[(((size_t)(n * G_ + g)) * 2 + ph) * 64 + k];
    float agg = 0.f;
    #pragma unroll
    for (int g = 0; g < 8; ++g)
        #pragma unroll
        for (int ph = 0; ph < 2; ++ph)
            agg += agg_part[(((((size_t)(n * G_ + g)) * 2 + ph) * 64) + k) * 128 + d];
    out[idx] = agg - ws * centroids[k * 128 + d];
}

// ---------------------------------------------------------------------------
extern "C" void kernel_launch(void* const* d_in, const int* in_sizes, int n_in,
                              void* d_out, int out_size, void* d_ws, size_t ws_size,
                              hipStream_t stream) {
    const float* x         = (const float*)d_in[0];
    const float* W1        = (const float*)d_in[1];
    const float* W2        = (const float*)d_in[2];
    const float* Wc        = (const float*)d_in[3];
    const float* centroids = (const float*)d_in[4];
    float* out = (float*)d_out;

    // Workspace layout (total <= 120,324,096 B proven footprint):
    //   W1b      [E*C]        bf16   1,048,576 B @ 0
    //   Vb       [G*K*C]      bf16     524,288 B @ 1,048,576
    //   xhat_t   [N*P*C]      bf16  33,554,432 B @ 1,572,864
    //   xe       [N*E*P]      bf16  67,108,864 B @ 35,127,296
    //   att_s    [N*G*P]      f32    1,048,576 B @ 102,236,160
    //   agg_part [N*G*2*K*D]  f32   16,777,216 B @ 103,284,736
    //   wsum_part[N*G*2*K]    f32      131,072 B @ 120,061,952
    //   Wa       [G*C]        bf16       8,192 B @ 120,193,024
    char* ws = (char*)d_ws;
    unsigned short* W1b      = (unsigned short*)(ws + 0);
    unsigned short* Vb       = (unsigned short*)(ws + 1048576);
    unsigned short* xhat_t   = (unsigned short*)(ws + 1572864);
    unsigned short* xe       = (unsigned short*)(ws + 35127296);
    float*          att_s    = (float*)(ws + 102236160);
    float*          agg_part = (float*)(ws + 103284736);
    float*          wsum_part= (float*)(ws + 120061952);
    unsigned short* Wa       = (unsigned short*)(ws + 120193024);

    hipLaunchKernelGGL(k0_prep,        dim3(1152), dim3(256), 0, stream, W1, Wc, W2, W1b, Vb, Wa);
    hipLaunchKernelGGL(k1_norm_att,    dim3(16, 32), dim3(256), 0, stream, x, Wa, xhat_t, att_s);
    hipLaunchKernelGGL(k2_gemm_xe,     dim3(64, 32), dim3(256), 0, stream, W1b, xhat_t, xe);
    hipLaunchKernelGGL(k4_assign_agg,  dim3(16, 32), dim3(512), 0, stream, Vb, xhat_t, xe,
                       att_s, agg_part, wsum_part);
    hipLaunchKernelGGL(k5_final,       dim3(1024), dim3(256), 0, stream,
                       agg_part, wsum_part, centroids, out);
}